// Round 7
// baseline (189.302 us; speedup 1.0000x reference)
//
#include <hip/hip_runtime.h>
#include <hip/hip_bf16.h>
#include <stdint.h>

#define BATCH 4
#define SEQ   2048
#define NC    1024
#define NH    16
#define HD    64
#define NT    16   // q-tiles of 128 rows

typedef __bf16 bf16x8 __attribute__((ext_vector_type(8)));
typedef __bf16 bf16x2 __attribute__((ext_vector_type(2)));
typedef float  f32x4  __attribute__((ext_vector_type(4)));
typedef float  f32x16 __attribute__((ext_vector_type(16)));

#define DEV __device__ __forceinline__

DEV unsigned short f2bf(float f) {
    union { float f; unsigned u; } v; v.f = f;
    unsigned r = (v.u + 0x7fffu + ((v.u >> 16) & 1u)) >> 16;
    return (unsigned short)r;
}

DEV float fast_exp2(float x) {
#if __has_builtin(__builtin_amdgcn_exp2f)
    return __builtin_amdgcn_exp2f(x);
#else
    return exp2f(x);
#endif
}

// (a', b') : a' = {a_lo, b_lo}, b' = {a_hi, b_hi}
DEV void plane32_swap(uint32_t& a, uint32_t& b) {
#if __has_builtin(__builtin_amdgcn_permlane32_swap)
    auto r = __builtin_amdgcn_permlane32_swap(a, b, false, false);
    a = (uint32_t)r[0];
    b = (uint32_t)r[1];
#else
    uint32_t sa = __shfl_xor(a, 32), sb = __shfl_xor(b, 32);
    const bool hi = ((threadIdx.x & 63) >= 32);
    uint32_t na = hi ? sb : a;
    uint32_t nb = hi ? b : sa;
    a = na; b = nb;
#endif
}

// async global->LDS, 16B per lane. LDS dest must be wave-uniform base; HW adds lane*16.
#define GLDS16(gsrc, ldst)                                                           \
    __builtin_amdgcn_global_load_lds(                                                \
        (const __attribute__((address_space(1))) unsigned int*)(gsrc),               \
        (__attribute__((address_space(3))) unsigned int*)(ldst), 16, 0, 0)

// ---------------------------------------------------------------------------
// fp32 -> bf16 convert (vectorized float4 -> ushort4)
// ---------------------------------------------------------------------------
__global__ void cvt_kernel(const float* __restrict__ in, unsigned short* __restrict__ out, int n4) {
    int i = blockIdx.x * 256 + threadIdx.x;
    if (i >= n4) return;
    float4 v = reinterpret_cast<const float4*>(in)[i];
    ushort4 o;
    o.x = f2bf(v.x); o.y = f2bf(v.y); o.z = f2bf(v.z); o.w = f2bf(v.w);
    reinterpret_cast<ushort4*>(out)[i] = o;
}

// ---------------------------------------------------------------------------
// C[M,N] = A[M,K] * W[N,K]^T + bias, bf16 inputs, fp32 accum. (unchanged)
// ---------------------------------------------------------------------------
template <bool BF16_OUT>
__global__ __launch_bounds__(256, 2) void gemm_bt_kernel(
    const unsigned short* __restrict__ A,
    const unsigned short* __restrict__ W,
    const float* __restrict__ bias,
    void* __restrict__ Cout,
    int M, int N, int K, int scale_n, float scale)
{
    __shared__ __align__(16) char Alds[128 * 128];
    __shared__ __align__(16) char Blds[128 * 128];

    const int tid = threadIdx.x;
    const int w = tid >> 6, l = tid & 63, g = l >> 4, lr = l & 15;
    const int nt = N >> 7;
    const int cpx = gridDim.x >> 3;
    const int bid = (blockIdx.x & 7) * cpx + (blockIdx.x >> 3);
    const int mtile = bid / nt, ntile = bid % nt;
    const int m0 = mtile << 7, n0 = ntile << 7;
    const int wr = (w >> 1) << 6, wc = (w & 1) << 6;

    f32x4 acc[4][4] = {};

    for (int kt = 0; kt < K; kt += 64) {
        if (kt) __syncthreads();
#pragma unroll
        for (int i = 0; i < 4; ++i) {
            const int issue = (i << 2) + w;
            const int row = (issue << 3) + (l >> 3);
            const int chunk = (l & 7) ^ (row & 7);
            GLDS16((const char*)(A + (size_t)(m0 + row) * K + kt) + (chunk << 4),
                   Alds + (issue << 10));
        }
#pragma unroll
        for (int i = 0; i < 4; ++i) {
            const int issue = (i << 2) + w;
            const int row = (issue << 3) + (l >> 3);
            const int chunk = (l & 7) ^ (row & 7);
            GLDS16((const char*)(W + (size_t)(n0 + row) * K + kt) + (chunk << 4),
                   Blds + (issue << 10));
        }
        __syncthreads();

#pragma unroll
        for (int kb = 0; kb < 2; ++kb) {
            bf16x8 af[4], bfr[4];
#pragma unroll
            for (int mf = 0; mf < 4; ++mf) {
                const int row = wr + (mf << 4) + lr;
                const int chunk = ((kb << 2) + g) ^ (row & 7);
                af[mf] = *reinterpret_cast<const bf16x8*>(Alds + row * 128 + (chunk << 4));
            }
#pragma unroll
            for (int nf = 0; nf < 4; ++nf) {
                const int row = wc + (nf << 4) + lr;
                const int chunk = ((kb << 2) + g) ^ (row & 7);
                bfr[nf] = *reinterpret_cast<const bf16x8*>(Blds + row * 128 + (chunk << 4));
            }
#pragma unroll
            for (int mf = 0; mf < 4; ++mf)
#pragma unroll
                for (int nf = 0; nf < 4; ++nf)
                    acc[mf][nf] = __builtin_amdgcn_mfma_f32_16x16x32_bf16(
                        af[mf], bfr[nf], acc[mf][nf], 0, 0, 0);
        }
    }

#pragma unroll
    for (int mf = 0; mf < 4; ++mf) {
#pragma unroll
        for (int nf = 0; nf < 4; ++nf) {
            const int n = n0 + wc + (nf << 4) + lr;
            const float bscale = (n < scale_n) ? scale : 1.0f;
            const float bv = bias[n];
#pragma unroll
            for (int r = 0; r < 4; ++r) {
                const int m = m0 + wr + (mf << 4) + (g << 2) + r;
                float v2 = (acc[mf][nf][r] + bv) * bscale;
                if (BF16_OUT)
                    ((unsigned short*)Cout)[(size_t)m * N + n] = f2bf(v2);
                else
                    ((float*)Cout)[(size_t)m * N + n] = v2;
            }
        }
    }
}

// ---------------------------------------------------------------------------
// Causal flash attention: uniform-work 8-wave blocks with intra-block KV split.
// Block (p,h,b), 512 thr. Group A (waves 0-3): q-tile p complete (2p+2 tiles)
// then HEAD of tile P=15-p (15-2p tiles) = 17 units. Group B (waves 4-7):
// TAIL of tile P (17 tiles incl. diagonal) = 17 units. Uniform 17 -> all
// 512 blocks (2/CU, 16 waves/CU) finish together. Epilogue: A deposits its
// tile-P partial (O,m,l) into its dead staging LDS; B merges (online-softmax
// combine) and writes tile P. Per-group K/V double-buffered staging (64KB).
// V^T swizzle f(row)=(row>>1)&7: writes 8-distinct/8-lane (optimal), reads
// 2-way (free). 32x32x16 MFMA, O^T accum, in-register P via permlane32_swap,
// defer-max, exp2 domain (log2e folded upstream), setprio on MFMA clusters.
// ---------------------------------------------------------------------------
__global__ __launch_bounds__(512, 4) void attn_kernel(
    const unsigned short* __restrict__ qkv,  // [B*S, 3072] bf16
    unsigned short* __restrict__ ctx)        // [B*S, 1024] bf16
{
    // [group][buf][0=K(chunk-swz), 1=V^T(row-swz)][8KB] = 64KB exactly.
    __shared__ __align__(16) char Stage[2][2][2][8192];

    const int tid = threadIdx.x;
    const int g = tid >> 8;                 // 0 = group A, 1 = group B
    const int tg = tid & 255;               // index within group
    const int w = tg >> 6;                  // group-local wave 0..3
    const int l = tid & 63, hi = l >> 5, lq = l & 31;
    const int bid = blockIdx.x;
    const int p = bid >> 6;                 // 0..7
    const int hb = bid & 63;
    const int h = hb >> 2, b = hb & 3;
    const int P = NT - 1 - p;               // 8..15
    const unsigned short* base = qkv + (size_t)b * SEQ * 3072 + h * 64;

    const int switch_t = 2 * p + 2;         // A: t < switch_t -> tile p
    const int jB0 = 15 - 2 * p;             // B's first kv-tile (>=1)

    // V staging coords: thread loads 8 keys x 2 d, writes 2 b128 rows.
    const int vkey0 = (tg >> 5) << 3;                  // logical key chunk*8
    const int vd0   = (tg & 31) << 1;                  // even d row
    const int vphys = ((tg >> 5) ^ (tg & 7)) << 4;     // chunk ^ f(row), f=(row>>1)&7
    const unsigned short* vbase = base + 2048 + (size_t)vkey0 * 3072 + vd0;

    int q0 = ((g == 0) ? p : P) * 128 + (w << 5);
    int q = q0 + lq;

    bf16x8 qfr[4];
#pragma unroll
    for (int ds = 0; ds < 4; ++ds)
        qfr[ds] = *reinterpret_cast<const bf16x8*>(
            base + (size_t)q * 3072 + (ds << 4) + (hi << 3));

    f32x16 acc0 = {}, acc1 = {};  // O^T: col(lq)=q, rows d / d+32
    float mrun = -INFINITY, lrun = 0.f;
    uint32_t vreg[8];

    // ---- prologue: stage first kv-tile into buf 0 ----
    {
        const int j0 = (g == 0) ? 0 : jB0;
#pragma unroll
        for (int i = 0; i < 8; ++i)
            vreg[i] = *reinterpret_cast<const uint32_t*>(
                vbase + (size_t)((j0 << 6) + i) * 3072);
#pragma unroll
        for (int i = 0; i < 2; ++i) {
            const int issue = (i << 2) + w;
            const int row = (issue << 3) + (l >> 3);
            const int chunk = (l & 7) ^ (row & 7);
            GLDS16((const char*)(base + 1024 + (size_t)((j0 << 6) + row) * 3072) + (chunk << 4),
                   &Stage[g][0][0][0] + (issue << 10));
        }
        uint4 a, bq;
        a.x = (vreg[0] & 0xffffu) | (vreg[1] << 16);
        a.y = (vreg[2] & 0xffffu) | (vreg[3] << 16);
        a.z = (vreg[4] & 0xffffu) | (vreg[5] << 16);
        a.w = (vreg[6] & 0xffffu) | (vreg[7] << 16);
        bq.x = (vreg[0] >> 16) | (vreg[1] & 0xffff0000u);
        bq.y = (vreg[2] >> 16) | (vreg[3] & 0xffff0000u);
        bq.z = (vreg[4] >> 16) | (vreg[5] & 0xffff0000u);
        bq.w = (vreg[6] >> 16) | (vreg[7] & 0xffff0000u);
        char* vt = &Stage[g][0][1][0];
        *reinterpret_cast<uint4*>(vt + vd0 * 128 + vphys) = a;
        *reinterpret_cast<uint4*>(vt + (vd0 + 1) * 128 + vphys) = bq;
    }
    __syncthreads();

    for (int t = 0; t < 17; ++t) {
        const int cur = t & 1;
        const int jc = (g == 0) ? ((t < switch_t) ? t : t - switch_t) : (jB0 + t);
        const int kv0 = jc << 6;
        const bool pf_ = (t + 1 < 17);

        if (pf_) {
            const int jn = (g == 0) ? ((t + 1 < switch_t) ? t + 1 : t + 1 - switch_t)
                                    : (jB0 + t + 1);
#pragma unroll
            for (int i = 0; i < 8; ++i)
                vreg[i] = *reinterpret_cast<const uint32_t*>(
                    vbase + (size_t)((jn << 6) + i) * 3072);
#pragma unroll
            for (int i = 0; i < 2; ++i) {
                const int issue = (i << 2) + w;
                const int row = (issue << 3) + (l >> 3);
                const int chunk = (l & 7) ^ (row & 7);
                GLDS16((const char*)(base + 1024 + (size_t)((jn << 6) + row) * 3072) + (chunk << 4),
                       &Stage[g][cur ^ 1][0][0] + (issue << 10));
            }
        }

        if (g == 0 && t == switch_t) {
            // finalize + write tile p, then reset state for tile P head
            const float li = 1.0f / lrun;
            unsigned short* op = ctx + (size_t)(b * SEQ + q) * NC + h * HD;
#pragma unroll
            for (int r = 0; r < 16; ++r) {
                const int d = (r & 3) + ((r >> 2) << 3) + (hi << 2);
                op[d] = f2bf(acc0[r] * li);
                op[d + 32] = f2bf(acc1[r] * li);
            }
            q0 = P * 128 + (w << 5);
            q = q0 + lq;
#pragma unroll
            for (int ds = 0; ds < 4; ++ds)
                qfr[ds] = *reinterpret_cast<const bf16x8*>(
                    base + (size_t)q * 3072 + (ds << 4) + (hi << 3));
#pragma unroll
            for (int r = 0; r < 16; ++r) { acc0[r] = 0.f; acc1[r] = 0.f; }
            mrun = -INFINITY; lrun = 0.f;
        }

        if (kv0 <= q0 + 31) {           // wave-uniform causal tile skip
            const bool do1 = (kv0 + 32 <= q0 + 31);
            const char* Kl = &Stage[g][cur][0][0];
            const char* Vl = &Stage[g][cur][1][0];

            // ---- QK^T (S^T = K * Q^T), 32x32x16: col=q, row=key ----
            f32x16 st0 = {}, st1 = {};
            __builtin_amdgcn_s_setprio(1);
#pragma unroll
            for (int ds = 0; ds < 4; ++ds) {
                const int chunk = (((ds << 1) + hi) ^ (lq & 7)) << 4;
                bf16x8 k0 = *reinterpret_cast<const bf16x8*>(Kl + lq * 128 + chunk);
                st0 = __builtin_amdgcn_mfma_f32_32x32x16_bf16(k0, qfr[ds], st0, 0, 0, 0);
            }
            if (do1) {
#pragma unroll
                for (int ds = 0; ds < 4; ++ds) {
                    const int chunk = (((ds << 1) + hi) ^ (lq & 7)) << 4;
                    bf16x8 k1 = *reinterpret_cast<const bf16x8*>(Kl + (lq + 32) * 128 + chunk);
                    st1 = __builtin_amdgcn_mfma_f32_32x32x16_bf16(k1, qfr[ds], st1, 0, 0, 0);
                }
            }
            __builtin_amdgcn_s_setprio(0);

            // ---- causal mask ----
            if (kv0 + 31 > q0) {
#pragma unroll
                for (int r = 0; r < 16; ++r) {
                    const int key = kv0 + ((r & 3) + ((r >> 2) << 3) + (hi << 2));
                    if (key > q) st0[r] = -INFINITY;
                }
            }
            if (do1 && kv0 + 63 > q0) {
#pragma unroll
                for (int r = 0; r < 16; ++r) {
                    const int key = kv0 + 32 + ((r & 3) + ((r >> 2) << 3) + (hi << 2));
                    if (key > q) st1[r] = -INFINITY;
                }
            }

            // ---- online softmax (exp2 domain), per-lane ----
            float mt = st0[0];
#pragma unroll
            for (int r = 1; r < 16; ++r) mt = fmaxf(mt, st0[r]);
            if (do1) {
#pragma unroll
                for (int r = 0; r < 16; ++r) mt = fmaxf(mt, st1[r]);
            }
            mt = fmaxf(mt, __shfl_xor(mt, 32));
            if (__any(mt > mrun + 8.0f)) {  // defer-max
                const float mnew = fmaxf(mrun, mt);
                const float corr = fast_exp2(mrun - mnew);
                mrun = mnew;
                lrun *= corr;
#pragma unroll
                for (int r = 0; r < 16; ++r) { acc0[r] *= corr; acc1[r] *= corr; }
            }
            float rs = 0.f;
#pragma unroll
            for (int r = 0; r < 16; ++r) { st0[r] = fast_exp2(st0[r] - mrun); rs += st0[r]; }
            if (do1) {
#pragma unroll
                for (int r = 0; r < 16; ++r) { st1[r] = fast_exp2(st1[r] - mrun); rs += st1[r]; }
            }
            rs += __shfl_xor(rs, 32);
            lrun += rs;

            // ---- pack P to bf16 pairs ----
            uint32_t pk0[8], pk1[8];
#pragma unroll
            for (int sp = 0; sp < 4; ++sp)
#pragma unroll
                for (int c = 0; c < 2; ++c) {
                    bf16x2 t0 = {(__bf16)st0[(sp << 2) + (c << 1)],
                                 (__bf16)st0[(sp << 2) + (c << 1) + 1]};
                    pk0[(sp << 1) + c] = __builtin_bit_cast(uint32_t, t0);
                }
            if (do1) {
#pragma unroll
                for (int sp = 0; sp < 4; ++sp)
#pragma unroll
                    for (int c = 0; c < 2; ++c) {
                        bf16x2 t1 = {(__bf16)st1[(sp << 2) + (c << 1)],
                                     (__bf16)st1[(sp << 2) + (c << 1) + 1]};
                        pk1[(sp << 1) + c] = __builtin_bit_cast(uint32_t, t1);
                    }
            }

            // ---- PV as O^T: in-reg P^T B-frag via permlane32_swap ----
            const int nkt = do1 ? 4 : 2;
            const int fch = (lq >> 1) & 7;   // V^T read: f(d)=(d>>1)&7, same for d and d+32
            __builtin_amdgcn_s_setprio(1);
#pragma unroll
            for (int kt = 0; kt < 4; ++kt) {
                if (kt >= nkt) break;
                const int s0 = (kt & 1) << 1;
                uint32_t x0, x1, y0, y1;
                if (kt < 2) {
                    x0 = pk0[(s0 << 1) + 0]; x1 = pk0[(s0 << 1) + 1];
                    y0 = pk0[(s0 << 1) + 2]; y1 = pk0[(s0 << 1) + 3];
                } else {
                    x0 = pk1[(s0 << 1) + 0]; x1 = pk1[(s0 << 1) + 1];
                    y0 = pk1[(s0 << 1) + 2]; y1 = pk1[(s0 << 1) + 3];
                }
                plane32_swap(x0, y0);
                plane32_swap(x1, y1);
                union { uint32_t u[4]; bf16x8 v; } pf;
                pf.u[0] = x0; pf.u[1] = x1; pf.u[2] = y0; pf.u[3] = y1;

                const int cc = (kt << 1) + hi;
                bf16x8 vf0 = *reinterpret_cast<const bf16x8*>(
                    Vl + lq * 128 + ((cc ^ fch) << 4));
                bf16x8 vf1 = *reinterpret_cast<const bf16x8*>(
                    Vl + (lq + 32) * 128 + ((cc ^ fch) << 4));
                acc0 = __builtin_amdgcn_mfma_f32_32x32x16_bf16(vf0, pf.v, acc0, 0, 0, 0);
                acc1 = __builtin_amdgcn_mfma_f32_32x32x16_bf16(vf1, pf.v, acc1, 0, 0, 0);
            }
            __builtin_amdgcn_s_setprio(0);
        }

        if (pf_) {
            uint4 a, bq;
            a.x = (vreg[0] & 0xffffu) | (vreg[1] << 16);
            a.y = (vreg[2] & 0xffffu) | (vreg[3] << 16);
            a.z = (vreg[4] & 0xffffu) | (vreg[5] << 16);
            a.w = (vreg[6] & 0xffffu) | (vreg[7] << 16);
            bq.x = (vreg[0] >> 16) | (vreg[1] & 0xffff0000u);
            bq.y = (vreg[2] >> 16) | (vreg[3] & 0xffff0000u);
            bq.z = (vreg[4] >> 16) | (vreg[5] & 0xffff0000u);
            bq.w = (vreg[6] >> 16) | (vreg[7] & 0xffff0000u);
            char* vt = &Stage[g][cur ^ 1][1][0];
            *reinterpret_cast<uint4*>(vt + vd0 * 128 + vphys) = a;
            *reinterpret_cast<uint4*>(vt + (vd0 + 1) * 128 + vphys) = bq;
            __syncthreads();
        }
    }

    // ---- merge: A deposits tile-P partial into dead staging LDS; B combines ----
    __syncthreads();   // all staging reads complete
    if (g == 0) {
        float* OA = (float*)&Stage[0][0][0][0];   // 256 lanes x 128B = 32KB
        const int L = (w << 6) + l;
        char* lb = (char*)OA + L * 128;
#pragma unroll
        for (int c = 0; c < 4; ++c) {
            f32x4 t4 = {acc0[(c << 2)], acc0[(c << 2) + 1], acc0[(c << 2) + 2], acc0[(c << 2) + 3]};
            *reinterpret_cast<f32x4*>(lb + ((c ^ (L & 7)) << 4)) = t4;
        }
#pragma unroll
        for (int c = 4; c < 8; ++c) {
            const int r0 = (c - 4) << 2;
            f32x4 t4 = {acc1[r0], acc1[r0 + 1], acc1[r0 + 2], acc1[r0 + 3]};
            *reinterpret_cast<f32x4*>(lb + ((c ^ (L & 7)) << 4)) = t4;
        }
        float* ml = (float*)&Stage[1][0][0][0];   // B's staging also dead
        if (hi == 0) {
            ml[(((w << 5) + lq) << 1) + 0] = mrun;
            ml[(((w << 5) + lq) << 1) + 1] = lrun;
        }
    }
    __syncthreads();
    if (g == 1) {
        const float* OA = (const float*)&Stage[0][0][0][0];
        const float* ml = (const float*)&Stage[1][0][0][0];
        const int L = (w << 6) + l;
        const char* lb = (const char*)OA + L * 128;
        f32x4 oa[8];
#pragma unroll
        for (int c = 0; c < 8; ++c)
            oa[c] = *reinterpret_cast<const f32x4*>(lb + ((c ^ (L & 7)) << 4));
        const float mA = ml[(((w << 5) + lq) << 1) + 0];
        const float lA = ml[(((w << 5) + lq) << 1) + 1];
        const float m2 = fmaxf(mA, mrun);
        float fa = fast_exp2(mA - m2);
        float fb = fast_exp2(mrun - m2);
        const float inv = 1.0f / (fa * lA + fb * lrun);
        fa *= inv; fb *= inv;
        unsigned short* op = ctx + (size_t)(b * SEQ + q) * NC + h * HD;
#pragma unroll
        for (int r = 0; r < 16; ++r) {
            const int d = (r & 3) + ((r >> 2) << 3) + (hi << 2);
            op[d]      = f2bf(fa * oa[r >> 2][r & 3]       + fb * acc0[r]);
            op[d + 32] = f2bf(fa * oa[4 + (r >> 2)][r & 3] + fb * acc1[r]);
        }
    }
}

// ---------------------------------------------------------------------------
extern "C" void kernel_launch(void* const* d_in, const int* in_sizes, int n_in,
                              void* d_out, int out_size, void* d_ws, size_t ws_size,
                              hipStream_t stream) {
    const float* x     = (const float*)d_in[0];
    const float* Wqkv  = (const float*)d_in[1];
    const float* bqkv  = (const float*)d_in[2];
    const float* Wproj = (const float*)d_in[3];
    const float* bproj = (const float*)d_in[4];
    float* out = (float*)d_out;

    const int M = BATCH * SEQ;  // 8192
    unsigned short* ws = (unsigned short*)d_ws;
    unsigned short* xb     = ws;                           // 8192*1024
    unsigned short* wqkvb  = xb + (size_t)M * NC;          // 3072*1024
    unsigned short* wprojb = wqkvb + (size_t)3 * NC * NC;  // 1024*1024
    unsigned short* qkvb   = wprojb + (size_t)NC * NC;     // 8192*3072
    unsigned short* ctxb   = qkvb + (size_t)M * 3 * NC;    // 8192*1024

    {
        int n4 = M * NC / 4;
        cvt_kernel<<<(n4 + 255) / 256, 256, 0, stream>>>(x, xb, n4);
    }
    {
        int n4 = 3 * NC * NC / 4;
        cvt_kernel<<<(n4 + 255) / 256, 256, 0, stream>>>(Wqkv, wqkvb, n4);
    }
    {
        int n4 = NC * NC / 4;
        cvt_kernel<<<(n4 + 255) / 256, 256, 0, stream>>>(Wproj, wprojb, n4);
    }

    // qkv = x @ Wqkv^T + b; q-third scaled by (1/sqrt(64))*log2(e) -> exp2 softmax
    gemm_bt_kernel<true><<<(M / 128) * (3 * NC / 128), 256, 0, stream>>>(
        xb, wqkvb, bqkv, qkvb, M, 3 * NC, NC, NC, 0.18033688011112042f);

    // 512 uniform blocks (17 kv-tile units each), 8 waves: A=tile p + P-head,
    // B=P-tail, in-LDS merge. bid = p*64 + hb keeps same-(h,b) on one XCD.
    attn_kernel<<<8 * NH * BATCH, 512, 0, stream>>>(qkvb, ctxb);

    // out = ctx @ Wproj^T + b (fp32 out)
    gemm_bt_kernel<false><<<(M / 128) * (NC / 128), 256, 0, stream>>>(
        ctxb, wprojb, bproj, out, M, NC, NC, 0, 1.0f);
}